// Round 3
// baseline (530.268 us; speedup 1.0000x reference)
//
#include <hip/hip_runtime.h>
#include <math.h>

#define NNODES 6000
#define NEDGES 192000
#define DIN 512
#define HDIM 128
#define ALPHA 1.0f
#define EOS 1e-10f
// Per-row edge-bucket capacity. Degree is Poisson(32) on a FIXED seed-0 input;
// P(any row > 256) is astronomically small. Overflow edges are dropped (never).
#define KMAX 256
// Paint chunk: 6000 = 6 x 1000 columns, 1000 floats = 250 float4 per array.
#define CHUNK 1000

// Native clang vector type — required by __builtin_nontemporal_store
// (HIP's float4 is a class and is rejected by the builtin).
typedef float f32x4 __attribute__((ext_vector_type(4)));

static const size_t NN = (size_t)NNODES * (size_t)NNODES;

// ---------------------------------------------------------------------------
// Kernel 1: per-node scalar g[i] = dot(relu(feat[i] @ w_emb + b_emb), wv)
// where wv[h] = 0.5*(w_mlp[h] + w_mlp[H+h]).  8 nodes per block, 128 threads
// (thread = h index).  Feature rows staged in LDS, consumed as float4
// broadcasts.  Also zeroes this block's 8 row counters (replaces the
// hipMemsetAsync dispatch).
// ---------------------------------------------------------------------------
__global__ __launch_bounds__(128) void embed_g_kernel(
    const float* __restrict__ feat, const float* __restrict__ w_emb,
    const float* __restrict__ b_emb, const float* __restrict__ w_mlp,
    float* __restrict__ g, int* __restrict__ cnt) {
  __shared__ float sf[8 * DIN];
  __shared__ float red[2][8];
  const int t = threadIdx.x;
  const int nb = blockIdx.x * 8;

  if (t < 8) cnt[nb + t] = 0;  // folded counter zeroing

  // stage 8 feature rows (contiguous: 4096 floats = 1024 float4)
  const float4* f4 = (const float4*)(feat + (size_t)nb * DIN);
  float4* s4 = (float4*)sf;
#pragma unroll
  for (int k = 0; k < 8; ++k) s4[k * 128 + t] = f4[k * 128 + t];
  __syncthreads();

  const int h = t;
  float acc[8];
  const float b = b_emb[h];
#pragma unroll
  for (int n = 0; n < 8; ++n) acc[n] = b;

  const float4* sf4 = (const float4*)sf;
#pragma unroll 2
  for (int d4 = 0; d4 < DIN / 4; ++d4) {
    const float w0 = w_emb[(d4 * 4 + 0) * HDIM + h];  // coalesced across h
    const float w1 = w_emb[(d4 * 4 + 1) * HDIM + h];
    const float w2 = w_emb[(d4 * 4 + 2) * HDIM + h];
    const float w3 = w_emb[(d4 * 4 + 3) * HDIM + h];
#pragma unroll
    for (int n = 0; n < 8; ++n) {
      const float4 f = sf4[n * (DIN / 4) + d4];  // LDS broadcast, b128
      acc[n] += f.x * w0;
      acc[n] += f.y * w1;
      acc[n] += f.z * w2;
      acc[n] += f.w * w3;
    }
  }

  const float wv = 0.5f * (w_mlp[h] + w_mlp[HDIM + h]);
  const int lane = t & 63, wave = t >> 6;
#pragma unroll
  for (int n = 0; n < 8; ++n) {
    float v = fmaxf(acc[n], 0.0f) * wv;
    for (int off = 32; off > 0; off >>= 1) v += __shfl_down(v, off, 64);
    if (lane == 0) red[wave][n] = v;
  }
  __syncthreads();
  if (t < 8) g[nb + t] = red[0][t] + red[1][t];
}

// ---------------------------------------------------------------------------
// Kernel 2: per-edge gate weights + row bucketing.  Per-row edge-id lists live
// at the START of each unnorm output row (as ints) — consumed by K3/K4 before
// the paint pass overwrites them; only the block owning row r reads row r's
// list, so there is no cross-block ordering hazard.
// ---------------------------------------------------------------------------
__global__ __launch_bounds__(256) void edge_bucket_kernel(
    const int* __restrict__ edges, const float* __restrict__ g,
    const float* __restrict__ noise, const float* __restrict__ b_mlp,
    float* __restrict__ w_lp, float* __restrict__ w_hp,
    int* __restrict__ cnt, int* __restrict__ slots) {
  const int e = blockIdx.x * blockDim.x + threadIdx.x;
  if (e >= NEDGES) return;
  const int u = edges[e];
  const int v = edges[NEDGES + e];
  const float raw = g[u] + g[v] + b_mlp[0];
  const float x = noise[e] + raw;  // TEMP == 1.0
  const float wl = 1.0f / (1.0f + __expf(-x));
  w_lp[e] = wl;
  w_hp[e] = 1.0f - wl;
  const int k = atomicAdd(&cnt[u], 1);  // 24-KB counter array, L2-resident
  if (k < KMAX) slots[(size_t)u * NNODES + k] = e;
}

// ---------------------------------------------------------------------------
// Kernel 3: per-row dedup (last-write-wins == max edge id, matching the JAX
// scatter-set semantics) + exact row-degree sums + inverse sqrt degrees
// (node_inv folded in — degree is wave-local here).  One wave per row,
// 4 rows per 256-thread block.  Rewrites each slot as packed
// (e<<14)|(v<<1)|win for the paint pass.
// ---------------------------------------------------------------------------
__global__ __launch_bounds__(256) void row_dedup_deg_kernel(
    const int* __restrict__ edges, const float* __restrict__ w_lp,
    const float* __restrict__ w_hp, const int* __restrict__ cnt,
    int* __restrict__ slots, float* __restrict__ inv_lp,
    float* __restrict__ inv_hp) {
  __shared__ int se[4][KMAX];
  __shared__ int sv[4][KMAX];
  __shared__ float sl[4][KMAX];
  __shared__ float sh[4][KMAX];
  const int wid = threadIdx.x >> 6;
  const int lane = threadIdx.x & 63;
  const int r = blockIdx.x * 4 + wid;  // grid = 1500 -> r always < NNODES

  int k = cnt[r];
  if (k > KMAX) k = KMAX;
  int* srow = slots + (size_t)r * NNODES;
  for (int i = lane; i < k; i += 64) {
    const int e = srow[i];
    se[wid][i] = e;
    sv[wid][i] = edges[NEDGES + e];
    sl[wid][i] = w_lp[e];
    sh[wid][i] = w_hp[e];
  }
  __syncthreads();  // also covers the (rare) cross-wave LDS visibility

  float suml = 0.0f, sumh = 0.0f;
  for (int i = lane; i < k; i += 64) {
    const int e = se[wid][i];
    const int v = sv[wid][i];
    int win = 1;
    for (int j = 0; j < k; ++j) {
      if (sv[wid][j] == v && se[wid][j] > e) { win = 0; break; }
    }
    if (win) {
      suml += sl[wid][i];
      sumh += sh[wid][i];
    }
    srow[i] = (e << 14) | (v << 1) | win;  // decode with unsigned >> 14
  }
  for (int off = 32; off > 0; off >>= 1) {
    suml += __shfl_down(suml, off, 64);
    sumh += __shfl_down(sumh, off, 64);
  }
  if (lane == 0) {
    inv_lp[r] = 1.0f / (sqrtf(suml + 1.0f) + EOS);  // +1 = eye
    inv_hp[r] = 1.0f / (sqrtf(sumh + 1.0f) + EOS);
  }
}

// ---------------------------------------------------------------------------
// Kernel 4: row paint — every output byte written EXACTLY ONCE, no RMW.
// Block r: decode row r's slot list (head of unnorm row r) into LDS entry
// lists, then for each 1000-column chunk: zero a 12-KB LDS chunk image,
// scatter the (few) edge/diag values into it, stream it out with nontemporal
// float4 stores.  Replaces zero-fill+override (whose override pass RMW'd
// ~198K already-evicted lines: ~25 MB fetch + 25 MB re-writeback).
// ---------------------------------------------------------------------------
__global__ __launch_bounds__(256) void paint_kernel(
    const float* __restrict__ w_lp, const float* __restrict__ w_hp,
    const float* __restrict__ inv_lp, const float* __restrict__ inv_hp,
    const int* __restrict__ cnt, float* __restrict__ adj_lp,
    float* __restrict__ adj_hp, float* __restrict__ unnorm) {
  __shared__ __align__(16) float chl[CHUNK];  // lp chunk image
  __shared__ __align__(16) float chh[CHUNK];  // hp chunk image
  __shared__ __align__(16) float chu[CHUNK];  // unnorm chunk image
  __shared__ int colw[KMAX + 1];              // winner cols (+default diag)
  __shared__ float vlp[KMAX + 1];
  __shared__ float vhp[KMAX + 1];
  __shared__ int colu[KMAX];                  // mask cols (all edges)
  __shared__ int skk, shas;

  const int t = threadIdx.x;
  const int r = blockIdx.x;
  int k = cnt[r];
  if (k > KMAX) k = KMAX;
  const float il = inv_lp[r];
  const float ih = inv_hp[r];

  float* lp_row = adj_lp + (size_t)r * NNODES;
  float* hp_row = adj_hp + (size_t)r * NNODES;
  float* un_row = unnorm + (size_t)r * NNODES;
  const int* srow = (const int*)un_row;  // packed slots from K3

  if (t == 0) shas = 0;
  __syncthreads();

  if (t < k) {
    const int raw = srow[t];
    const int win = raw & 1;
    const int v = (raw >> 1) & 0x1FFF;
    const int e = (int)(((unsigned)raw) >> 14);
    const float wl = w_lp[e];
    const float wh = w_hp[e];
    colu[t] = v;                     // mask: every edge occurrence
    if (v == r) shas = 1;            // benign same-value LDS race
    if (win) {
      if (v == r) {                  // winning self-edge: diagonal values
        colw[t] = r;
        vlp[t] = (wl + 1.0f) * il * il;
        vhp[t] = 1.0f - (wh + 1.0f) * ih * ih * ALPHA;
      } else {
        colw[t] = v;
        vlp[t] = wl * il * inv_lp[v];
        vhp[t] = -ALPHA * wh * ih * inv_hp[v];
      }
    } else {
      colw[t] = -1;                  // non-winner: no lp/hp contribution
    }
  }
  __syncthreads();  // slot loads from un_row complete before any store to it

  if (t == 0) {
    if (!shas) {  // eye-only diagonal
      colw[k] = r;
      vlp[k] = il * il;
      vhp[k] = 1.0f;
      skk = k + 1;
    } else {
      skk = k;
    }
  }
  __syncthreads();
  const int kk = skk;

  const f32x4 z = {0.0f, 0.0f, 0.0f, 0.0f};
  f32x4* chl4 = (f32x4*)chl;
  f32x4* chh4 = (f32x4*)chh;
  f32x4* chu4 = (f32x4*)chu;

  for (int c0 = 0; c0 < NNODES; c0 += CHUNK) {
    if (t < CHUNK / 4) {
      chl4[t] = z;
      chh4[t] = z;
      chu4[t] = z;
    }
    __syncthreads();
    for (int j = t; j < kk; j += 256) {
      const int d = colw[j] - c0;
      if ((unsigned)d < (unsigned)CHUNK) {
        chl[d] = vlp[j];
        chh[d] = vhp[j];
      }
    }
    for (int j = t; j < k; j += 256) {
      const int d = colu[j] - c0;
      if ((unsigned)d < (unsigned)CHUNK) chu[d] = 1.0f;
    }
    __syncthreads();
    if (t < CHUNK / 4) {
      const f32x4 L = chl4[t];
      const f32x4 H = chh4[t];
      const f32x4 U = chu4[t];
      __builtin_nontemporal_store(L, (f32x4*)(lp_row + c0) + t);
      __builtin_nontemporal_store(H, (f32x4*)(hp_row + c0) + t);
      __builtin_nontemporal_store(U, (f32x4*)(un_row + c0) + t);
    }
    __syncthreads();  // LDS images consumed before next chunk's zeroing
  }
}

extern "C" void kernel_launch(void* const* d_in, const int* in_sizes, int n_in,
                              void* d_out, int out_size, void* d_ws,
                              size_t ws_size, hipStream_t stream) {
  const float* feat  = (const float*)d_in[0];
  const int*   edges = (const int*)d_in[1];
  const float* w_emb = (const float*)d_in[2];
  const float* b_emb = (const float*)d_in[3];
  const float* w_mlp = (const float*)d_in[4];
  const float* b_mlp = (const float*)d_in[5];
  const float* noise = (const float*)d_in[6];

  float* out    = (float*)d_out;
  float* adj_lp = out;                 // [N,N]
  float* adj_hp = out + NN;            // [N,N]
  float* w_lp   = out + 2 * NN;        // [E]
  float* w_hp   = w_lp + NEDGES;       // [E]
  float* unnorm = w_hp + NEDGES;       // [N,N] (heads double as slot lists)

  // workspace: 4 x 24 KB = 96 KB
  float* g      = (float*)d_ws;        // [N]
  float* inv_lp = g + NNODES;          // [N]
  float* inv_hp = inv_lp + NNODES;     // [N]
  int*   cnt    = (int*)(inv_hp + NNODES);  // [N]

  // 4 dispatches, zero memsets: counter zeroing folded into embed, inverse
  // degrees folded into dedup, every output byte written once by paint.
  embed_g_kernel<<<NNODES / 8, 128, 0, stream>>>(feat, w_emb, b_emb, w_mlp, g,
                                                 cnt);

  edge_bucket_kernel<<<NEDGES / 256, 256, 0, stream>>>(
      edges, g, noise, b_mlp, w_lp, w_hp, cnt, (int*)unnorm);

  row_dedup_deg_kernel<<<NNODES / 4, 256, 0, stream>>>(
      edges, w_lp, w_hp, cnt, (int*)unnorm, inv_lp, inv_hp);

  paint_kernel<<<NNODES, 256, 0, stream>>>(w_lp, w_hp, inv_lp, inv_hp, cnt,
                                           adj_lp, adj_hp, unnorm);
}

// Round 4
// 513.720 us; speedup vs baseline: 1.0322x; 1.0322x over previous
//
#include <hip/hip_runtime.h>
#include <math.h>

#define NNODES 6000
#define NEDGES 192000
#define DIN 512
#define HDIM 128
#define ALPHA 1.0f
#define EOS 1e-10f
// Per-row edge-bucket capacity. Degree is Poisson(32) on a FIXED seed-0 input;
// P(any row > 256) is astronomically small. Overflow edges are dropped (never).
#define KMAX 256

// Native clang vector type — required by __builtin_nontemporal_store
// (HIP's float4 is a class and is rejected by the builtin).
typedef float f32x4 __attribute__((ext_vector_type(4)));

static const size_t NN = (size_t)NNODES * (size_t)NNODES;

// ---------------------------------------------------------------------------
// Kernel 1: per-node scalar g[i] = dot(relu(feat[i] @ w_emb + b_emb), wv)
// where wv[h] = 0.5*(w_mlp[h] + w_mlp[H+h]).  8 nodes per block, 128 threads
// (thread = h index).  Feature rows staged in LDS, consumed as float4
// broadcasts.  Also zeroes this block's 8 row counters.
// ---------------------------------------------------------------------------
__global__ __launch_bounds__(128) void embed_g_kernel(
    const float* __restrict__ feat, const float* __restrict__ w_emb,
    const float* __restrict__ b_emb, const float* __restrict__ w_mlp,
    float* __restrict__ g, int* __restrict__ cnt) {
  __shared__ float sf[8 * DIN];
  __shared__ float red[2][8];
  const int t = threadIdx.x;
  const int nb = blockIdx.x * 8;

  if (t < 8) cnt[nb + t] = 0;  // folded counter zeroing

  // stage 8 feature rows (contiguous: 4096 floats = 1024 float4)
  const float4* f4 = (const float4*)(feat + (size_t)nb * DIN);
  float4* s4 = (float4*)sf;
#pragma unroll
  for (int k = 0; k < 8; ++k) s4[k * 128 + t] = f4[k * 128 + t];
  __syncthreads();

  const int h = t;
  float acc[8];
  const float b = b_emb[h];
#pragma unroll
  for (int n = 0; n < 8; ++n) acc[n] = b;

  const float4* sf4 = (const float4*)sf;
#pragma unroll 2
  for (int d4 = 0; d4 < DIN / 4; ++d4) {
    const float w0 = w_emb[(d4 * 4 + 0) * HDIM + h];  // coalesced across h
    const float w1 = w_emb[(d4 * 4 + 1) * HDIM + h];
    const float w2 = w_emb[(d4 * 4 + 2) * HDIM + h];
    const float w3 = w_emb[(d4 * 4 + 3) * HDIM + h];
#pragma unroll
    for (int n = 0; n < 8; ++n) {
      const float4 f = sf4[n * (DIN / 4) + d4];  // LDS broadcast, b128
      acc[n] += f.x * w0;
      acc[n] += f.y * w1;
      acc[n] += f.z * w2;
      acc[n] += f.w * w3;
    }
  }

  const float wv = 0.5f * (w_mlp[h] + w_mlp[HDIM + h]);
  const int lane = t & 63, wave = t >> 6;
#pragma unroll
  for (int n = 0; n < 8; ++n) {
    float v = fmaxf(acc[n], 0.0f) * wv;
    for (int off = 32; off > 0; off >>= 1) v += __shfl_down(v, off, 64);
    if (lane == 0) red[wave][n] = v;
  }
  __syncthreads();
  if (t < 8) g[nb + t] = red[0][t] + red[1][t];
}

// ---------------------------------------------------------------------------
// Kernel 2: per-edge gate weights + row bucketing.  Slot lists now live in
// the WORKSPACE (row stride KMAX ints = 1 KB, 6 MB total, L2-friendly) —
// the output region is no longer used for transient data, which decouples
// slot-list lifetime from unnorm-row painting (enables matrix-split paint).
// ---------------------------------------------------------------------------
__global__ __launch_bounds__(256) void edge_bucket_kernel(
    const int* __restrict__ edges, const float* __restrict__ g,
    const float* __restrict__ noise, const float* __restrict__ b_mlp,
    float* __restrict__ w_lp, float* __restrict__ w_hp,
    int* __restrict__ cnt, int* __restrict__ slots) {
  const int e = blockIdx.x * blockDim.x + threadIdx.x;
  if (e >= NEDGES) return;
  const int u = edges[e];
  const int v = edges[NEDGES + e];
  const float raw = g[u] + g[v] + b_mlp[0];
  const float x = noise[e] + raw;  // TEMP == 1.0
  const float wl = 1.0f / (1.0f + __expf(-x));
  w_lp[e] = wl;
  w_hp[e] = 1.0f - wl;
  const int k = atomicAdd(&cnt[u], 1);  // 24-KB counter array, L2-resident
  if (k < KMAX) slots[u * KMAX + k] = e;
}

// ---------------------------------------------------------------------------
// Kernel 3: per-row dedup (last-write-wins == max edge id, matching JAX
// scatter-set semantics) + row-degree sums + inverse sqrt degrees.  One wave
// per row, 4 rows per block.  Rewrites each slot as packed
// (e<<14)|(v<<1)|win (decode e via unsigned >> 14).
// ---------------------------------------------------------------------------
__global__ __launch_bounds__(256) void row_dedup_deg_kernel(
    const int* __restrict__ edges, const float* __restrict__ w_lp,
    const float* __restrict__ w_hp, const int* __restrict__ cnt,
    int* __restrict__ slots, float* __restrict__ inv_lp,
    float* __restrict__ inv_hp) {
  __shared__ int se[4][KMAX];
  __shared__ int sv[4][KMAX];
  __shared__ float sl[4][KMAX];
  __shared__ float sh[4][KMAX];
  const int wid = threadIdx.x >> 6;
  const int lane = threadIdx.x & 63;
  const int r = blockIdx.x * 4 + wid;  // grid = 1500 -> r always < NNODES

  int k = cnt[r];
  if (k > KMAX) k = KMAX;
  int* srow = slots + r * KMAX;
  for (int i = lane; i < k; i += 64) {
    const int e = srow[i];
    se[wid][i] = e;
    sv[wid][i] = edges[NEDGES + e];
    sl[wid][i] = w_lp[e];
    sh[wid][i] = w_hp[e];
  }
  __syncthreads();

  float suml = 0.0f, sumh = 0.0f;
  for (int i = lane; i < k; i += 64) {
    const int e = se[wid][i];
    const int v = sv[wid][i];
    int win = 1;
    for (int j = 0; j < k; ++j) {
      if (sv[wid][j] == v && se[wid][j] > e) { win = 0; break; }
    }
    if (win) {
      suml += sl[wid][i];
      sumh += sh[wid][i];
    }
    srow[i] = (e << 14) | (v << 1) | win;
  }
  for (int off = 32; off > 0; off >>= 1) {
    suml += __shfl_down(suml, off, 64);
    sumh += __shfl_down(sumh, off, 64);
  }
  if (lane == 0) {
    inv_lp[r] = 1.0f / (sqrtf(suml + 1.0f) + EOS);  // +1 = eye
    inv_hp[r] = 1.0f / (sqrtf(sumh + 1.0f) + EOS);
  }
}

// ---------------------------------------------------------------------------
// Kernel 4: matrix-split row paint.  Block b -> matrix m = b/6000 (0=lp,
// 1=hp, 2=un), row r = b%6000.  Composes the FULL 24-KB row image in LDS
// (one zero pass + <=kk scatters), then streams it as ONE contiguous
// nontemporal burst — 2 barriers/block, a single long store stream per
// block, all 256 lanes active.  This mirrors the fill kernel's access
// pattern (which measures 6.2-6.3 TB/s), replacing the previous
// 3-interleaved-streams / 18-barriers-per-block structure.
// ---------------------------------------------------------------------------
__global__ __launch_bounds__(256) void paint_kernel(
    const float* __restrict__ w_lp, const float* __restrict__ w_hp,
    const float* __restrict__ inv_lp, const float* __restrict__ inv_hp,
    const int* __restrict__ cnt, const int* __restrict__ slots,
    float* __restrict__ adj_lp, float* __restrict__ adj_hp,
    float* __restrict__ unnorm) {
  __shared__ __align__(16) float img[NNODES];  // 24 KB row image
  __shared__ int col[KMAX + 1];
  __shared__ float val[KMAX + 1];
  __shared__ int skk, shas;
  __shared__ float sdiag;  // winning self-edge weight (this matrix's w)

  const int t = threadIdx.x;
  const int b = blockIdx.x;
  const int m = b / NNODES;      // 0=lp, 1=hp, 2=un
  const int r = b - m * NNODES;

  int k = cnt[r];
  if (k > KMAX) k = KMAX;

  if (t == 0) {
    shas = 0;
    sdiag = 0.0f;
  }
  __syncthreads();

  const int* srow = slots + r * KMAX;
  const float il = inv_lp[r];
  const float ih = inv_hp[r];

  // zero the image (LDS region disjoint from col/val — safe to interleave
  // with the decode below; the single barrier after covers both)
  f32x4* img4 = (f32x4*)img;
  const f32x4 z = {0.0f, 0.0f, 0.0f, 0.0f};
  for (int i = t; i < NNODES / 4; i += 256) img4[i] = z;

  if (t < k) {
    const int raw = srow[t];
    const int win = raw & 1;
    const int v = (raw >> 1) & 0x1FFF;
    const int e = (int)(((unsigned)raw) >> 14);
    if (m == 2) {
      col[t] = v;       // mask: every edge occurrence writes 1.0
      val[t] = 1.0f;
    } else {
      const float w = (m == 0) ? w_lp[e] : w_hp[e];
      if (v == r) {
        shas = 1;                 // benign same-value LDS race
        if (win) sdiag = w;       // unique writer: winning self-edge
        col[t] = -1;              // diagonal handled below
      } else if (win) {
        col[t] = v;
        val[t] = (m == 0) ? w * il * inv_lp[v]
                          : -ALPHA * w * ih * inv_hp[v];
      } else {
        col[t] = -1;              // non-winner duplicate: no contribution
      }
    }
  }
  __syncthreads();

  if (t == 0) {
    if (m == 0) {        // lp diag: (w_self + 1) * il^2  (w_self=0 if none)
      col[k] = r;
      val[k] = (sdiag + 1.0f) * il * il;
      skk = k + 1;
    } else if (m == 1) { // hp diag: 1 - (w_self+1)*ih^2 if self-edge else 1
      col[k] = r;
      val[k] = shas ? (1.0f - (sdiag + 1.0f) * ih * ih * ALPHA) : 1.0f;
      skk = k + 1;
    } else {             // un diag: only set by an actual self-edge above
      skk = k;
    }
  }
  __syncthreads();

  const int kk = skk;
  for (int j = t; j < kk; j += 256) {
    const int c = col[j];
    if (c >= 0) img[c] = val[j];
  }
  __syncthreads();

  float* dst = (m == 0 ? adj_lp : (m == 1 ? adj_hp : unnorm)) +
               (size_t)r * NNODES;
  for (int i = t; i < NNODES / 4; i += 256)
    __builtin_nontemporal_store(img4[i], (f32x4*)dst + i);
}

extern "C" void kernel_launch(void* const* d_in, const int* in_sizes, int n_in,
                              void* d_out, int out_size, void* d_ws,
                              size_t ws_size, hipStream_t stream) {
  const float* feat  = (const float*)d_in[0];
  const int*   edges = (const int*)d_in[1];
  const float* w_emb = (const float*)d_in[2];
  const float* b_emb = (const float*)d_in[3];
  const float* w_mlp = (const float*)d_in[4];
  const float* b_mlp = (const float*)d_in[5];
  const float* noise = (const float*)d_in[6];

  float* out    = (float*)d_out;
  float* adj_lp = out;                 // [N,N]
  float* adj_hp = out + NN;            // [N,N]
  float* w_lp   = out + 2 * NN;        // [E]
  float* w_hp   = w_lp + NEDGES;       // [E]
  float* unnorm = w_hp + NEDGES;       // [N,N]

  // workspace: 96 KB of node arrays + 6 MB slot lists
  float* g      = (float*)d_ws;        // [N]
  float* inv_lp = g + NNODES;          // [N]
  float* inv_hp = inv_lp + NNODES;     // [N]
  int*   cnt    = (int*)(inv_hp + NNODES);  // [N]
  int*   slots  = cnt + NNODES;        // [N][KMAX]

  // 4 dispatches, zero memsets; every output byte written exactly once.
  embed_g_kernel<<<NNODES / 8, 128, 0, stream>>>(feat, w_emb, b_emb, w_mlp, g,
                                                 cnt);

  edge_bucket_kernel<<<NEDGES / 256, 256, 0, stream>>>(
      edges, g, noise, b_mlp, w_lp, w_hp, cnt, slots);

  row_dedup_deg_kernel<<<NNODES / 4, 256, 0, stream>>>(
      edges, w_lp, w_hp, cnt, slots, inv_lp, inv_hp);

  paint_kernel<<<3 * NNODES, 256, 0, stream>>>(w_lp, w_hp, inv_lp, inv_hp,
                                               cnt, slots, adj_lp, adj_hp,
                                               unnorm);
}